// Round 19
// baseline (152.128 us; speedup 1.0000x reference)
//
#include <hip/hip_runtime.h>
#include <hip/hip_bf16.h>

// EdgeProbMLP: out[e] = sigmoid( relu( [x*y, x-y] @ W1.T + b1 ) @ W2.T + b2 )
// x = relu(nf[src] @ Wdim.T + bdim), y = same for dst.
// P[n] = relu(proj(nf[n])) precomputed once (f16, d_ws).
// R19 = R18 (3-buffer counted-vmcnt pipeline, W1 f16 strips in regs, async
// global_load_lds gather, f16 packed math, dual accumulators) + ONE change:
// b1/W2 epilogue tables hoisted from LDS to 32 VGPRs. R18's ledger: VALU
// 50%, MFMA 26%, and ~50% LDS-pipe busy (24 ds_read_b128/tile/wave, 8 of
// which are the loop-invariant table reads sitting on the epilogue critical
// path behind lgkm waits). Hoist costs +32 VGPR: 84 -> ~116 < 128 quantum
// (R18 proved occupancy holds there). Epilogue becomes pure VALU; LDS
// traffic -33%. Guard: WRITE_SIZE must stay ~3.9MB (no spill).

#define N_NODES 100000
#define N_EDGES 1000000
#define NT      31250     // 1M / 32 edges per tile
#define GRID    768       // 3 blocks/CU

typedef unsigned int u32;
typedef u32   u32x2 __attribute__((ext_vector_type(2)));
typedef u32   u32x4 __attribute__((ext_vector_type(4)));
typedef float f32x4 __attribute__((ext_vector_type(4)));
typedef float f32x16 __attribute__((ext_vector_type(16)));
typedef __bf16 bf16x8 __attribute__((ext_vector_type(8)));
typedef _Float16 f16x8 __attribute__((ext_vector_type(8)));

__device__ inline u32 pack2bf(float a, float b) {
    unsigned short ua = __builtin_bit_cast(unsigned short, (__bf16)a);
    unsigned short ub = __builtin_bit_cast(unsigned short, (__bf16)b);
    return (u32)ua | ((u32)ub << 16);
}
__device__ inline u32 pack2h(float a, float b) {
    unsigned short ua = __builtin_bit_cast(unsigned short, (_Float16)a);
    unsigned short ub = __builtin_bit_cast(unsigned short, (_Float16)b);
    return (u32)ua | ((u32)ub << 16);
}

// async gather: per-lane global src, HW writes LDS at (uniform base + lane*16)
__device__ __forceinline__ void gload16(const unsigned char* g, unsigned char* l) {
    __builtin_amdgcn_global_load_lds(
        (__attribute__((address_space(1))) unsigned int*)g,
        (__attribute__((address_space(3))) unsigned int*)l,
        16, 0, 0);
}

// ---------------------------------------------------------------------------
// Kernel 1: P[n][c] = relu(sum_k nf[n][k] * Wdim[c][k] + bdim[c]), F16 out.
// ---------------------------------------------------------------------------
__global__ __launch_bounds__(256, 1) void k_project(
    const float* __restrict__ nf, const float* __restrict__ Wdim,
    const float* __restrict__ bdim, unsigned short* __restrict__ P)
{
    __shared__ unsigned char lA[128 * 256];  // 32 KB: Wdim as bf16 [128ch][128k]
    const int t = threadIdx.x;
    for (int ci = t; ci < 2048; ci += 256) {
        const int row = ci >> 4;
        const int k8 = (ci & 15) << 3;
        const float* wp = Wdim + (row << 7) + k8;
        f32x4 v0 = *(const f32x4*)wp;
        f32x4 v1 = *(const f32x4*)(wp + 4);
        u32x4 pk = { pack2bf(v0[0], v0[1]), pack2bf(v0[2], v0[3]),
                     pack2bf(v1[0], v1[1]), pack2bf(v1[2], v1[3]) };
        int byte = (row << 8) + (k8 << 1);
        byte ^= (row & 15) << 4;
        *(u32x4*)(lA + byte) = pk;
    }
    __syncthreads();

    const int lane = t & 63;
    const int wave = t >> 6;
    const int cc = lane & 31;
    const int h  = lane >> 5;
    const int tile = blockIdx.x * 4 + wave;
    if (tile >= 3125) return;
    const int node = (tile << 5) + cc;
    const float* xrow = nf + ((size_t)node << 7);

    f32x4 rv[16];
#pragma unroll
    for (int kt = 0; kt < 8; ++kt) {
        const int kf = (kt << 4) + (h << 3);
        rv[2*kt]   = *(const f32x4*)(xrow + kf);
        rv[2*kt+1] = *(const f32x4*)(xrow + kf + 4);
    }

    f32x16 acc[4] = {};
#pragma unroll
    for (int kt = 0; kt < 8; ++kt) {
        const int kf = (kt << 4) + (h << 3);
        f32x4 v0 = rv[2*kt], v1 = rv[2*kt+1];
        bf16x8 bf;
        bf[0]=(__bf16)v0[0]; bf[1]=(__bf16)v0[1]; bf[2]=(__bf16)v0[2]; bf[3]=(__bf16)v0[3];
        bf[4]=(__bf16)v1[0]; bf[5]=(__bf16)v1[1]; bf[6]=(__bf16)v1[2]; bf[7]=(__bf16)v1[3];
        const int off = kf << 1;
#pragma unroll
        for (int t4 = 0; t4 < 4; ++t4) {
            const int arow = (t4 << 5) + cc;
            const int ab = ((arow << 8) + off) ^ ((arow & 15) << 4);
            bf16x8 af = __builtin_bit_cast(bf16x8, *(const u32x4*)(lA + ab));
            acc[t4] = __builtin_amdgcn_mfma_f32_32x32x16_bf16(af, bf, acc[t4], 0, 0, 0);
        }
    }
    unsigned short* prow = P + ((size_t)node << 7);
#pragma unroll
    for (int t4 = 0; t4 < 4; ++t4) {
#pragma unroll
        for (int q = 0; q < 4; ++q) {
            const int chb = (t4 << 5) + (q << 3) + (h << 2);
            f32x4 bb = *(const f32x4*)(bdim + chb);
            const float h0 = fmaxf(acc[t4][(q << 2) + 0] + bb[0], 0.f);
            const float h1 = fmaxf(acc[t4][(q << 2) + 1] + bb[1], 0.f);
            const float h2 = fmaxf(acc[t4][(q << 2) + 2] + bb[2], 0.f);
            const float h3 = fmaxf(acc[t4][(q << 2) + 3] + bb[3], 0.f);
            u32x2 st = { pack2h(h0, h1), pack2h(h2, h3) };   // F16 store
            *(u32x2*)(prow + chb) = st;
        }
    }
}

// ---------------------------------------------------------------------------
// Kernel 2: block-cooperative 32-edge tiles, f16 packed math, 3-buffer
// counted-vmcnt pipeline, dual accumulators, b1/W2 in registers.
// Rows: r=0..31 src (x), r=32..63 dst (y); buf[r][c16] holds global chunk
// c ^ (r&15) (source-side swizzle). Wave w stages rows [w*16, w*16+16).
// ---------------------------------------------------------------------------
__global__ __launch_bounds__(256, 2) void k_edge(
    const unsigned short* __restrict__ P,
    const int* __restrict__ ei,          // [2][E] int32
    const float* __restrict__ W1, const float* __restrict__ B1,
    const float* __restrict__ W2, const float* __restrict__ B2,
    float* __restrict__ out)
{
    __shared__ unsigned char b0[64 * 256];   // 16 KB each, static names
    __shared__ unsigned char b1[64 * 256];
    __shared__ unsigned char b2[64 * 256];
    __shared__ float pr[2][4][32];           // per-wave partials (phase dbuf)
    const int t = threadIdx.x;
    const int lane = t & 63;
    const int wave = t >> 6;
    const int cc = lane & 31;     // edge column / A-row
    const int h  = lane >> 5;     // k-half

    // ---- W1 strip -> f16 registers: wave w owns channels [w*32, w*32+32).
    f16x8 wf[16];
    {
        const float* wrow = W1 + (((wave << 5) + cc) << 8);   // 256 f32/row
#pragma unroll
        for (int kt = 0; kt < 8; ++kt) {
#pragma unroll
            for (int half = 0; half < 2; ++half) {
                const float* wp = wrow + (half << 7) + (kt << 4) + (h << 3);
                f32x4 a = *(const f32x4*)wp;
                f32x4 b = *(const f32x4*)(wp + 4);
                f16x8 f;
                f[0]=(_Float16)a[0]; f[1]=(_Float16)a[1]; f[2]=(_Float16)a[2]; f[3]=(_Float16)a[3];
                f[4]=(_Float16)b[0]; f[5]=(_Float16)b[1]; f[6]=(_Float16)b[2]; f[7]=(_Float16)b[3];
                wf[(kt << 1) + half] = f;
            }
        }
    }

    // ---- b1/W2 epilogue tables -> 32 VGPRs (loop-invariant; R19 change)
    f32x4 bbr[4], wwr[4];
#pragma unroll
    for (int q = 0; q < 4; ++q) {
        const int chb = (wave << 5) + (q << 3) + (h << 2);
        bbr[q] = *(const f32x4*)(B1 + chb);
        wwr[q] = *(const f32x4*)(W2 + chb);
    }

    // staging geometry: instr i covers rows wave*16+i*4+(lane>>4);
    // slot chunk c = lane&15, global chunk = c ^ (r&15)
    const unsigned char* Pb = (const unsigned char*)P;
    const int* eb = ei + (wave < 2 ? 0 : N_EDGES - 32);   // dst waves offset
    const int rl = lane >> 4;
    const int rb0 = (wave << 4) + 0  + rl, rb1 = (wave << 4) + 4  + rl;
    const int rb2 = (wave << 4) + 8  + rl, rb3 = (wave << 4) + 12 + rl;
    const int xo0 = ((lane & 15) ^ (rb0 & 15)) << 4;
    const int xo1 = ((lane & 15) ^ (rb1 & 15)) << 4;
    const int xo2 = ((lane & 15) ^ (rb2 & 15)) << 4;
    const int xo3 = ((lane & 15) ^ (rb3 & 15)) << 4;
    const int lbo0 = (rb0 & ~3) << 8, lbo1 = (rb1 & ~3) << 8;
    const int lbo2 = (rb2 & ~3) << 8, lbo3 = (rb3 & ~3) << 8;
    const int cx = cc & 15;
    const float b2v = B2[0];
    const int t0 = blockIdx.x;

    int tl = t0, prev = -1, ph = 0;
    int nidx0, nidx1, nidx2, nidx3;

    // ---- prologue: stage T0->b0, T1->b1; load nidx for T2; one full drain.
    {
        const int* e0 = eb + (t0 << 5);
        int i0 = e0[rb0], i1 = e0[rb1], i2 = e0[rb2], i3 = e0[rb3];
        gload16(Pb + ((size_t)i0 << 8) + xo0, b0 + lbo0);
        gload16(Pb + ((size_t)i1 << 8) + xo1, b0 + lbo1);
        gload16(Pb + ((size_t)i2 << 8) + xo2, b0 + lbo2);
        gload16(Pb + ((size_t)i3 << 8) + xo3, b0 + lbo3);
    }
    {
        int tn = t0 + GRID; tn = tn < NT ? tn : NT - 1;
        const int* e1 = eb + (tn << 5);
        int i0 = e1[rb0], i1 = e1[rb1], i2 = e1[rb2], i3 = e1[rb3];
        gload16(Pb + ((size_t)i0 << 8) + xo0, b1 + lbo0);
        gload16(Pb + ((size_t)i1 << 8) + xo1, b1 + lbo1);
        gload16(Pb + ((size_t)i2 << 8) + xo2, b1 + lbo2);
        gload16(Pb + ((size_t)i3 << 8) + xo3, b1 + lbo3);
    }
    {
        int tn = t0 + 2 * GRID; tn = tn < NT ? tn : NT - 1;
        const int* e2 = eb + (tn << 5);
        nidx0 = e2[rb0]; nidx1 = e2[rb1]; nidx2 = e2[rb2]; nidx3 = e2[rb3];
    }
    __syncthreads();   // prologue drain: b0,b1 staged

// One step: barrier (no vmcnt drain) -> store prev tile -> stage tl+2*GRID
// into BS (consumes nidx => compiler wait retires LAST step's loads — the
// counted-wait) -> load nidx for tl+3*GRID -> compute tl from BC with dual
// accumulators -> pure-VALU epilogue (tables in regs) -> lgkmcnt(0).
#define STEP(BC, BS)                                                          \
    {                                                                         \
        asm volatile("s_waitcnt vmcnt(8)\n\ts_barrier" ::: "memory");         \
        if (prev >= 0 && t < 32) {                                            \
            const int pp = ph ^ 1;                                            \
            const float z = pr[pp][0][t] + pr[pp][1][t] + pr[pp][2][t]        \
                          + pr[pp][3][t] + b2v;                               \
            out[(prev << 5) + t] = 1.0f / (1.0f + __expf(-z));                \
        }                                                                     \
        gload16(Pb + ((size_t)nidx0 << 8) + xo0, (BS) + lbo0);                \
        gload16(Pb + ((size_t)nidx1 << 8) + xo1, (BS) + lbo1);                \
        gload16(Pb + ((size_t)nidx2 << 8) + xo2, (BS) + lbo2);                \
        gload16(Pb + ((size_t)nidx3 << 8) + xo3, (BS) + lbo3);                \
        {   int tn = tl + 3 * GRID; tn = tn < NT ? tn : NT - 1;               \
            const int* ebn = eb + (tn << 5);                                  \
            nidx0 = ebn[rb0]; nidx1 = ebn[rb1];                               \
            nidx2 = ebn[rb2]; nidx3 = ebn[rb3]; }                             \
        const unsigned char* xb = (BC) + (cc << 8);                           \
        const unsigned char* yb = (BC) + ((32 + cc) << 8);                    \
        f32x16 accp = {}, accd = {};                                          \
        _Pragma("unroll")                                                     \
        for (int kt = 0; kt < 8; ++kt) {                                      \
            const int co = (((kt << 1) + h) ^ cx) << 4;                       \
            const f16x8 xh = __builtin_bit_cast(f16x8, *(const u32x4*)(xb + co)); \
            const f16x8 yh = __builtin_bit_cast(f16x8, *(const u32x4*)(yb + co)); \
            const f16x8 bpv = xh * yh;                                        \
            const f16x8 bdv = xh - yh;                                        \
            accp = __builtin_amdgcn_mfma_f32_32x32x16_f16(wf[(kt << 1) + 0], bpv, accp, 0, 0, 0); \
            accd = __builtin_amdgcn_mfma_f32_32x32x16_f16(wf[(kt << 1) + 1], bdv, accd, 0, 0, 0); \
        }                                                                     \
        float partial = 0.f;                                                  \
        _Pragma("unroll")                                                     \
        for (int q = 0; q < 4; ++q) {                                         \
            _Pragma("unroll")                                                 \
            for (int rr = 0; rr < 4; ++rr) {                                  \
                const float hv = fmaxf(accp[(q << 2) + rr] + accd[(q << 2) + rr] + bbr[q][rr], 0.f); \
                partial += hv * wwr[q][rr];                                   \
            }                                                                 \
        }                                                                     \
        partial += __shfl_xor(partial, 32);                                   \
        if (h == 0) pr[ph][wave][cc] = partial;                               \
        asm volatile("s_waitcnt lgkmcnt(0)" ::: "memory");                    \
        prev = tl; tl += GRID; ph ^= 1;                                       \
    }

    while (tl < NT) {
        STEP(b0, b2);
        if (tl >= NT) break;
        STEP(b1, b0);
        if (tl >= NT) break;
        STEP(b2, b1);
    }
#undef STEP

    // ---- epilogue: store the last computed tile's output
    asm volatile("s_barrier" ::: "memory");
    if (prev >= 0 && t < 32) {
        const int pp = ph ^ 1;
        const float z = pr[pp][0][t] + pr[pp][1][t] + pr[pp][2][t]
                      + pr[pp][3][t] + b2v;
        out[(prev << 5) + t] = 1.0f / (1.0f + __expf(-z));
    }
}

extern "C" void kernel_launch(void* const* d_in, const int* in_sizes, int n_in,
                              void* d_out, int out_size, void* d_ws, size_t ws_size,
                              hipStream_t stream) {
    const float* nf   = (const float*)d_in[0];
    const int*   ei   = (const int*)d_in[1];
    const float* Wdim = (const float*)d_in[2];
    const float* bdim = (const float*)d_in[3];
    const float* W1   = (const float*)d_in[4];
    const float* b1   = (const float*)d_in[5];
    const float* W2   = (const float*)d_in[6];
    const float* b2   = (const float*)d_in[7];
    float* out = (float*)d_out;
    unsigned short* P = (unsigned short*)d_ws;        // 100000*128 f16 = 25.6 MB

    k_project<<<dim3(782), dim3(256), 0, stream>>>(nf, Wdim, bdim, P);
    k_edge<<<dim3(GRID), dim3(256), 0, stream>>>(P, ei, W1, b1, W2, b2, out);
}

// Round 20
// 140.135 us; speedup vs baseline: 1.0856x; 1.0856x over previous
//
#include <hip/hip_runtime.h>
#include <hip/hip_bf16.h>

// EdgeProbMLP: out[e] = sigmoid( relu( [x*y, x-y] @ W1.T + b1 ) @ W2.T + b2 )
// x = relu(nf[src] @ Wdim.T + bdim), y = same for dst.
// P[n] = relu(proj(nf[n])) precomputed once (f16, d_ws).
// R20: (a) k_edge reverted to R18 EXACTLY (best stable: 112us, VGPR 84,
// occupancy 28%). R19's +32-reg hoist mapped the boundary: arch+acc must
// stay <=128 (116 ok / 136 collapses a block). k_edge is pinned at the
// ~2.0 TB/s random-gather service ceiling (1.95-2.03 TB/s across 3 pipeline
// configs; step-time arithmetic matches within 5%).
// (b) k_project loads fixed: old code read 16B/lane at 512B stride (fully
// uncoalesced). Now: per-wave nf tile (32 rows x 512B) staged via 16x
// global_load_lds — source-side XOR chunk permutation makes each instr two
// contiguous 512B spans (fully coalesced); ds_read back with mirrored XOR
// (4-way bank conflict, acceptable). Predict k_project ~21 -> ~14us.

#define N_NODES 100000
#define N_EDGES 1000000
#define NT      31250     // 1M / 32 edges per tile
#define GRID    768       // 3 blocks/CU

typedef unsigned int u32;
typedef u32   u32x2 __attribute__((ext_vector_type(2)));
typedef u32   u32x4 __attribute__((ext_vector_type(4)));
typedef float f32x4 __attribute__((ext_vector_type(4)));
typedef float f32x16 __attribute__((ext_vector_type(16)));
typedef __bf16 bf16x8 __attribute__((ext_vector_type(8)));
typedef _Float16 f16x8 __attribute__((ext_vector_type(8)));

__device__ inline u32 pack2bf(float a, float b) {
    unsigned short ua = __builtin_bit_cast(unsigned short, (__bf16)a);
    unsigned short ub = __builtin_bit_cast(unsigned short, (__bf16)b);
    return (u32)ua | ((u32)ub << 16);
}
__device__ inline u32 pack2h(float a, float b) {
    unsigned short ua = __builtin_bit_cast(unsigned short, (_Float16)a);
    unsigned short ub = __builtin_bit_cast(unsigned short, (_Float16)b);
    return (u32)ua | ((u32)ub << 16);
}

// async gather: per-lane global src, HW writes LDS at (uniform base + lane*16)
__device__ __forceinline__ void gload16(const unsigned char* g, unsigned char* l) {
    __builtin_amdgcn_global_load_lds(
        (__attribute__((address_space(1))) unsigned int*)g,
        (__attribute__((address_space(3))) unsigned int*)l,
        16, 0, 0);
}

// ---------------------------------------------------------------------------
// Kernel 1: P[n][c] = relu(sum_k nf[n][k] * Wdim[c][k] + bdim[c]), F16 out.
// R20: nf tile staged into LDS via coalesced global_load_lds (was strided).
// ---------------------------------------------------------------------------
__global__ __launch_bounds__(256, 1) void k_project(
    const float* __restrict__ nf, const float* __restrict__ Wdim,
    const float* __restrict__ bdim, unsigned short* __restrict__ P)
{
    __shared__ unsigned char lA[128 * 256];      // 32 KB: Wdim bf16 swizzled
    __shared__ unsigned char tiles[4][16384];    // 64 KB: per-wave nf tiles
    const int t = threadIdx.x;
    const int lane = t & 63;
    const int wave = t >> 6;
    const int cc = lane & 31;
    const int h  = lane >> 5;

    // ---- stage nf tile per wave: 16 gload16, each = two contiguous 512B
    // spans (rows 2i, 2i+1). LDS slot c of row r holds global chunk c ^ r.
    int tile = blockIdx.x * 4 + wave;
    const bool valid = tile < 3125;
    if (!valid) tile = 3124;                     // clamp: stage safely
    {
        const unsigned char* nfB = (const unsigned char*)nf;
        const size_t base = ((size_t)tile << 5) << 9;   // node_base * 512
        unsigned char* myT = tiles[wave];
        const int rr_ = lane >> 5;               // row parity within instr
        const int cs  = lane & 31;               // chunk slot
#pragma unroll
        for (int i = 0; i < 16; ++i) {
            const int r = (i << 1) + rr_;
            const int cg = cs ^ r;               // source-side permutation
            gload16(nfB + base + ((size_t)r << 9) + (cg << 4),
                    myT + (i << 10));
        }
    }

    // ---- stage Wdim -> lA (unchanged)
    for (int ci = t; ci < 2048; ci += 256) {
        const int row = ci >> 4;
        const int k8 = (ci & 15) << 3;
        const float* wp = Wdim + (row << 7) + k8;
        f32x4 v0 = *(const f32x4*)wp;
        f32x4 v1 = *(const f32x4*)(wp + 4);
        u32x4 pk = { pack2bf(v0[0], v0[1]), pack2bf(v0[2], v0[3]),
                     pack2bf(v1[0], v1[1]), pack2bf(v1[2], v1[3]) };
        int byte = (row << 8) + (k8 << 1);
        byte ^= (row & 15) << 4;
        *(u32x4*)(lA + byte) = pk;
    }
    __syncthreads();   // drains gload16 (vmcnt) + lA writes

    const unsigned char* myT = tiles[wave];
    f32x16 acc[4] = {};
#pragma unroll
    for (int kt = 0; kt < 8; ++kt) {             // K = 128 = 8 * 16
        const int g0 = (kt << 2) + (h << 1);     // global chunk of 8 f32
        f32x4 v0 = *(const f32x4*)(myT + (cc << 9) + (((g0    ) ^ cc) << 4));
        f32x4 v1 = *(const f32x4*)(myT + (cc << 9) + (((g0 + 1) ^ cc) << 4));
        bf16x8 bf;
        bf[0]=(__bf16)v0[0]; bf[1]=(__bf16)v0[1]; bf[2]=(__bf16)v0[2]; bf[3]=(__bf16)v0[3];
        bf[4]=(__bf16)v1[0]; bf[5]=(__bf16)v1[1]; bf[6]=(__bf16)v1[2]; bf[7]=(__bf16)v1[3];
        const int off = ((kt << 4) + (h << 3)) << 1;   // byte off in lA row
#pragma unroll
        for (int t4 = 0; t4 < 4; ++t4) {
            const int arow = (t4 << 5) + cc;
            const int ab = ((arow << 8) + off) ^ ((arow & 15) << 4);
            bf16x8 af = __builtin_bit_cast(bf16x8, *(const u32x4*)(lA + ab));
            acc[t4] = __builtin_amdgcn_mfma_f32_32x32x16_bf16(af, bf, acc[t4], 0, 0, 0);
        }
    }
    if (!valid) return;
    const int node = (tile << 5) + cc;
    unsigned short* prow = P + ((size_t)node << 7);
#pragma unroll
    for (int t4 = 0; t4 < 4; ++t4) {
#pragma unroll
        for (int q = 0; q < 4; ++q) {
            const int chb = (t4 << 5) + (q << 3) + (h << 2);
            f32x4 bb = *(const f32x4*)(bdim + chb);
            const float h0 = fmaxf(acc[t4][(q << 2) + 0] + bb[0], 0.f);
            const float h1 = fmaxf(acc[t4][(q << 2) + 1] + bb[1], 0.f);
            const float h2 = fmaxf(acc[t4][(q << 2) + 2] + bb[2], 0.f);
            const float h3 = fmaxf(acc[t4][(q << 2) + 3] + bb[3], 0.f);
            u32x2 st = { pack2h(h0, h1), pack2h(h2, h3) };   // F16 store
            *(u32x2*)(prow + chb) = st;
        }
    }
}

// ---------------------------------------------------------------------------
// Kernel 2: R18 verbatim — block-cooperative 32-edge tiles, f16 packed math,
// 3-buffer counted-vmcnt pipeline, dual accumulators, b1/W2 in LDS tables.
// Rows: r=0..31 src (x), r=32..63 dst (y); buf[r][c16] holds global chunk
// c ^ (r&15) (source-side swizzle). Wave w stages rows [w*16, w*16+16).
// ---------------------------------------------------------------------------
__global__ __launch_bounds__(256, 2) void k_edge(
    const unsigned short* __restrict__ P,
    const int* __restrict__ ei,          // [2][E] int32
    const float* __restrict__ W1, const float* __restrict__ B1,
    const float* __restrict__ W2, const float* __restrict__ B2,
    float* __restrict__ out)
{
    __shared__ unsigned char b0[64 * 256];   // 16 KB each, static names
    __shared__ unsigned char b1[64 * 256];
    __shared__ unsigned char b2[64 * 256];
    __shared__ float pr[2][4][32];           // per-wave partials (phase dbuf)
    __shared__ float sb1[128], sw2[128];
    const int t = threadIdx.x;
    const int lane = t & 63;
    const int wave = t >> 6;
    const int cc = lane & 31;     // edge column / A-row
    const int h  = lane >> 5;     // k-half
    if (t < 128) { sb1[t] = B1[t]; sw2[t] = W2[t]; }

    // ---- W1 strip -> f16 registers: wave w owns channels [w*32, w*32+32).
    f16x8 wf[16];
    {
        const float* wrow = W1 + (((wave << 5) + cc) << 8);   // 256 f32/row
#pragma unroll
        for (int kt = 0; kt < 8; ++kt) {
#pragma unroll
            for (int half = 0; half < 2; ++half) {
                const float* wp = wrow + (half << 7) + (kt << 4) + (h << 3);
                f32x4 a = *(const f32x4*)wp;
                f32x4 b = *(const f32x4*)(wp + 4);
                f16x8 f;
                f[0]=(_Float16)a[0]; f[1]=(_Float16)a[1]; f[2]=(_Float16)a[2]; f[3]=(_Float16)a[3];
                f[4]=(_Float16)b[0]; f[5]=(_Float16)b[1]; f[6]=(_Float16)b[2]; f[7]=(_Float16)b[3];
                wf[(kt << 1) + half] = f;
            }
        }
    }

    // staging geometry: instr i covers rows wave*16+i*4+(lane>>4);
    // slot chunk c = lane&15, global chunk = c ^ (r&15)
    const unsigned char* Pb = (const unsigned char*)P;
    const int* eb = ei + (wave < 2 ? 0 : N_EDGES - 32);   // dst waves offset
    const int rl = lane >> 4;
    const int rb0 = (wave << 4) + 0  + rl, rb1 = (wave << 4) + 4  + rl;
    const int rb2 = (wave << 4) + 8  + rl, rb3 = (wave << 4) + 12 + rl;
    const int xo0 = ((lane & 15) ^ (rb0 & 15)) << 4;
    const int xo1 = ((lane & 15) ^ (rb1 & 15)) << 4;
    const int xo2 = ((lane & 15) ^ (rb2 & 15)) << 4;
    const int xo3 = ((lane & 15) ^ (rb3 & 15)) << 4;
    const int lbo0 = (rb0 & ~3) << 8, lbo1 = (rb1 & ~3) << 8;
    const int lbo2 = (rb2 & ~3) << 8, lbo3 = (rb3 & ~3) << 8;
    const int cx = cc & 15;
    const float b2v = B2[0];
    const int t0 = blockIdx.x;

    int tl = t0, prev = -1, ph = 0;
    int nidx0, nidx1, nidx2, nidx3;

    // ---- prologue: stage T0->b0, T1->b1; load nidx for T2; one full drain.
    {
        const int* e0 = eb + (t0 << 5);
        int i0 = e0[rb0], i1 = e0[rb1], i2 = e0[rb2], i3 = e0[rb3];
        gload16(Pb + ((size_t)i0 << 8) + xo0, b0 + lbo0);
        gload16(Pb + ((size_t)i1 << 8) + xo1, b0 + lbo1);
        gload16(Pb + ((size_t)i2 << 8) + xo2, b0 + lbo2);
        gload16(Pb + ((size_t)i3 << 8) + xo3, b0 + lbo3);
    }
    {
        int tn = t0 + GRID; tn = tn < NT ? tn : NT - 1;
        const int* e1 = eb + (tn << 5);
        int i0 = e1[rb0], i1 = e1[rb1], i2 = e1[rb2], i3 = e1[rb3];
        gload16(Pb + ((size_t)i0 << 8) + xo0, b1 + lbo0);
        gload16(Pb + ((size_t)i1 << 8) + xo1, b1 + lbo1);
        gload16(Pb + ((size_t)i2 << 8) + xo2, b1 + lbo2);
        gload16(Pb + ((size_t)i3 << 8) + xo3, b1 + lbo3);
    }
    {
        int tn = t0 + 2 * GRID; tn = tn < NT ? tn : NT - 1;
        const int* e2 = eb + (tn << 5);
        nidx0 = e2[rb0]; nidx1 = e2[rb1]; nidx2 = e2[rb2]; nidx3 = e2[rb3];
    }
    __syncthreads();   // prologue drain: b0,b1 staged, tables ready

// One step: barrier (no vmcnt drain) -> store prev tile -> stage tl+2*GRID
// into BS (consumes nidx => compiler wait retires LAST step's loads — the
// counted-wait) -> load nidx for tl+3*GRID -> compute tl from BC with dual
// accumulators -> partials -> lgkmcnt(0).
#define STEP(BC, BS)                                                          \
    {                                                                         \
        asm volatile("s_waitcnt vmcnt(8)\n\ts_barrier" ::: "memory");         \
        if (prev >= 0 && t < 32) {                                            \
            const int pp = ph ^ 1;                                            \
            const float z = pr[pp][0][t] + pr[pp][1][t] + pr[pp][2][t]        \
                          + pr[pp][3][t] + b2v;                               \
            out[(prev << 5) + t] = 1.0f / (1.0f + __expf(-z));                \
        }                                                                     \
        gload16(Pb + ((size_t)nidx0 << 8) + xo0, (BS) + lbo0);                \
        gload16(Pb + ((size_t)nidx1 << 8) + xo1, (BS) + lbo1);                \
        gload16(Pb + ((size_t)nidx2 << 8) + xo2, (BS) + lbo2);                \
        gload16(Pb + ((size_t)nidx3 << 8) + xo3, (BS) + lbo3);                \
        {   int tn = tl + 3 * GRID; tn = tn < NT ? tn : NT - 1;               \
            const int* ebn = eb + (tn << 5);                                  \
            nidx0 = ebn[rb0]; nidx1 = ebn[rb1];                               \
            nidx2 = ebn[rb2]; nidx3 = ebn[rb3]; }                             \
        const unsigned char* xb = (BC) + (cc << 8);                           \
        const unsigned char* yb = (BC) + ((32 + cc) << 8);                    \
        f32x16 accp = {}, accd = {};                                          \
        _Pragma("unroll")                                                     \
        for (int kt = 0; kt < 8; ++kt) {                                      \
            const int co = (((kt << 1) + h) ^ cx) << 4;                       \
            const f16x8 xh = __builtin_bit_cast(f16x8, *(const u32x4*)(xb + co)); \
            const f16x8 yh = __builtin_bit_cast(f16x8, *(const u32x4*)(yb + co)); \
            const f16x8 bpv = xh * yh;                                        \
            const f16x8 bdv = xh - yh;                                        \
            accp = __builtin_amdgcn_mfma_f32_32x32x16_f16(wf[(kt << 1) + 0], bpv, accp, 0, 0, 0); \
            accd = __builtin_amdgcn_mfma_f32_32x32x16_f16(wf[(kt << 1) + 1], bdv, accd, 0, 0, 0); \
        }                                                                     \
        float partial = 0.f;                                                  \
        _Pragma("unroll")                                                     \
        for (int q = 0; q < 4; ++q) {                                         \
            const int chb = (wave << 5) + (q << 3) + (h << 2);                \
            const f32x4 bb = *(const f32x4*)(sb1 + chb);                      \
            const f32x4 ww = *(const f32x4*)(sw2 + chb);                      \
            _Pragma("unroll")                                                 \
            for (int rr = 0; rr < 4; ++rr) {                                  \
                const float hv = fmaxf(accp[(q << 2) + rr] + accd[(q << 2) + rr] + bb[rr], 0.f); \
                partial += hv * ww[rr];                                       \
            }                                                                 \
        }                                                                     \
        partial += __shfl_xor(partial, 32);                                   \
        if (h == 0) pr[ph][wave][cc] = partial;                               \
        asm volatile("s_waitcnt lgkmcnt(0)" ::: "memory");                    \
        prev = tl; tl += GRID; ph ^= 1;                                       \
    }

    while (tl < NT) {
        STEP(b0, b2);
        if (tl >= NT) break;
        STEP(b1, b0);
        if (tl >= NT) break;
        STEP(b2, b1);
    }
#undef STEP

    // ---- epilogue: store the last computed tile's output
    asm volatile("s_barrier" ::: "memory");
    if (prev >= 0 && t < 32) {
        const int pp = ph ^ 1;
        const float z = pr[pp][0][t] + pr[pp][1][t] + pr[pp][2][t]
                      + pr[pp][3][t] + b2v;
        out[(prev << 5) + t] = 1.0f / (1.0f + __expf(-z));
    }
}

extern "C" void kernel_launch(void* const* d_in, const int* in_sizes, int n_in,
                              void* d_out, int out_size, void* d_ws, size_t ws_size,
                              hipStream_t stream) {
    const float* nf   = (const float*)d_in[0];
    const int*   ei   = (const int*)d_in[1];
    const float* Wdim = (const float*)d_in[2];
    const float* bdim = (const float*)d_in[3];
    const float* W1   = (const float*)d_in[4];
    const float* b1   = (const float*)d_in[5];
    const float* W2   = (const float*)d_in[6];
    const float* b2   = (const float*)d_in[7];
    float* out = (float*)d_out;
    unsigned short* P = (unsigned short*)d_ws;        // 100000*128 f16 = 25.6 MB

    k_project<<<dim3(782), dim3(256), 0, stream>>>(nf, Wdim, bdim, P);
    k_edge<<<dim3(GRID), dim3(256), 0, stream>>>(P, ei, W1, b1, W2, b2, out);
}

// Round 21
// 133.365 us; speedup vs baseline: 1.1407x; 1.0508x over previous
//
#include <hip/hip_runtime.h>
#include <hip/hip_bf16.h>

// EdgeProbMLP: out[e] = sigmoid( relu( [x*y, x-y] @ W1.T + b1 ) @ W2.T + b2 )
// x = relu(nf[src] @ Wdim.T + bdim), y = same for dst.
// P[n] = relu(proj(nf[n])) precomputed once (f16, d_ws).
// R21 = R18 VERBATIM (measured best: 133.5us total, k_edge 112us).
// Final state. Ledger:
//  - k_edge: random-256B-gather service ceiling (1.95-2.03 TB/s across six
//    pipeline configs R14-R19; step-time arithmetic matches within 5%).
//    Levers tested: occupancy (R15 neutral), stage depth (R17 neg via reg
//    quantum), dual-acc (R18 neutral), table hoist (R19 neg via reg
//    quantum). Register boundary mapped: arch+acc <= 128/wave for
//    3 blocks/CU at 51KB LDS.
//  - k_project: ~80% of streaming roofline (21us vs 17us ideal for 103MB);
//    LDS-coalesced staging variant tested in R20 and regressed (serial
//    stage drain + 1 block/CU).

#define N_NODES 100000
#define N_EDGES 1000000
#define NT      31250     // 1M / 32 edges per tile
#define GRID    768       // 3 blocks/CU

typedef unsigned int u32;
typedef u32   u32x2 __attribute__((ext_vector_type(2)));
typedef u32   u32x4 __attribute__((ext_vector_type(4)));
typedef float f32x4 __attribute__((ext_vector_type(4)));
typedef float f32x16 __attribute__((ext_vector_type(16)));
typedef __bf16 bf16x8 __attribute__((ext_vector_type(8)));
typedef _Float16 f16x8 __attribute__((ext_vector_type(8)));

__device__ inline u32 pack2bf(float a, float b) {
    unsigned short ua = __builtin_bit_cast(unsigned short, (__bf16)a);
    unsigned short ub = __builtin_bit_cast(unsigned short, (__bf16)b);
    return (u32)ua | ((u32)ub << 16);
}
__device__ inline u32 pack2h(float a, float b) {
    unsigned short ua = __builtin_bit_cast(unsigned short, (_Float16)a);
    unsigned short ub = __builtin_bit_cast(unsigned short, (_Float16)b);
    return (u32)ua | ((u32)ub << 16);
}

// async gather: per-lane global src, HW writes LDS at (uniform base + lane*16)
__device__ __forceinline__ void gload16(const unsigned char* g, unsigned char* l) {
    __builtin_amdgcn_global_load_lds(
        (__attribute__((address_space(1))) unsigned int*)g,
        (__attribute__((address_space(3))) unsigned int*)l,
        16, 0, 0);
}

// ---------------------------------------------------------------------------
// Kernel 1: P[n][c] = relu(sum_k nf[n][k] * Wdim[c][k] + bdim[c]), F16 out.
// ---------------------------------------------------------------------------
__global__ __launch_bounds__(256, 1) void k_project(
    const float* __restrict__ nf, const float* __restrict__ Wdim,
    const float* __restrict__ bdim, unsigned short* __restrict__ P)
{
    __shared__ unsigned char lA[128 * 256];  // 32 KB: Wdim as bf16 [128ch][128k]
    const int t = threadIdx.x;
    for (int ci = t; ci < 2048; ci += 256) {
        const int row = ci >> 4;
        const int k8 = (ci & 15) << 3;
        const float* wp = Wdim + (row << 7) + k8;
        f32x4 v0 = *(const f32x4*)wp;
        f32x4 v1 = *(const f32x4*)(wp + 4);
        u32x4 pk = { pack2bf(v0[0], v0[1]), pack2bf(v0[2], v0[3]),
                     pack2bf(v1[0], v1[1]), pack2bf(v1[2], v1[3]) };
        int byte = (row << 8) + (k8 << 1);
        byte ^= (row & 15) << 4;
        *(u32x4*)(lA + byte) = pk;
    }
    __syncthreads();

    const int lane = t & 63;
    const int wave = t >> 6;
    const int cc = lane & 31;
    const int h  = lane >> 5;
    const int tile = blockIdx.x * 4 + wave;
    if (tile >= 3125) return;
    const int node = (tile << 5) + cc;
    const float* xrow = nf + ((size_t)node << 7);

    f32x4 rv[16];
#pragma unroll
    for (int kt = 0; kt < 8; ++kt) {
        const int kf = (kt << 4) + (h << 3);
        rv[2*kt]   = *(const f32x4*)(xrow + kf);
        rv[2*kt+1] = *(const f32x4*)(xrow + kf + 4);
    }

    f32x16 acc[4] = {};
#pragma unroll
    for (int kt = 0; kt < 8; ++kt) {
        const int kf = (kt << 4) + (h << 3);
        f32x4 v0 = rv[2*kt], v1 = rv[2*kt+1];
        bf16x8 bf;
        bf[0]=(__bf16)v0[0]; bf[1]=(__bf16)v0[1]; bf[2]=(__bf16)v0[2]; bf[3]=(__bf16)v0[3];
        bf[4]=(__bf16)v1[0]; bf[5]=(__bf16)v1[1]; bf[6]=(__bf16)v1[2]; bf[7]=(__bf16)v1[3];
        const int off = kf << 1;
#pragma unroll
        for (int t4 = 0; t4 < 4; ++t4) {
            const int arow = (t4 << 5) + cc;
            const int ab = ((arow << 8) + off) ^ ((arow & 15) << 4);
            bf16x8 af = __builtin_bit_cast(bf16x8, *(const u32x4*)(lA + ab));
            acc[t4] = __builtin_amdgcn_mfma_f32_32x32x16_bf16(af, bf, acc[t4], 0, 0, 0);
        }
    }
    unsigned short* prow = P + ((size_t)node << 7);
#pragma unroll
    for (int t4 = 0; t4 < 4; ++t4) {
#pragma unroll
        for (int q = 0; q < 4; ++q) {
            const int chb = (t4 << 5) + (q << 3) + (h << 2);
            f32x4 bb = *(const f32x4*)(bdim + chb);
            const float h0 = fmaxf(acc[t4][(q << 2) + 0] + bb[0], 0.f);
            const float h1 = fmaxf(acc[t4][(q << 2) + 1] + bb[1], 0.f);
            const float h2 = fmaxf(acc[t4][(q << 2) + 2] + bb[2], 0.f);
            const float h3 = fmaxf(acc[t4][(q << 2) + 3] + bb[3], 0.f);
            u32x2 st = { pack2h(h0, h1), pack2h(h2, h3) };   // F16 store
            *(u32x2*)(prow + chb) = st;
        }
    }
}

// ---------------------------------------------------------------------------
// Kernel 2: block-cooperative 32-edge tiles, f16 packed math, 3-buffer
// counted-vmcnt pipeline, dual accumulators, b1/W2 in LDS tables.
// Rows: r=0..31 src (x), r=32..63 dst (y); buf[r][c16] holds global chunk
// c ^ (r&15) (source-side swizzle). Wave w stages rows [w*16, w*16+16).
// ---------------------------------------------------------------------------
__global__ __launch_bounds__(256, 2) void k_edge(
    const unsigned short* __restrict__ P,
    const int* __restrict__ ei,          // [2][E] int32
    const float* __restrict__ W1, const float* __restrict__ B1,
    const float* __restrict__ W2, const float* __restrict__ B2,
    float* __restrict__ out)
{
    __shared__ unsigned char b0[64 * 256];   // 16 KB each, static names
    __shared__ unsigned char b1[64 * 256];
    __shared__ unsigned char b2[64 * 256];
    __shared__ float pr[2][4][32];           // per-wave partials (phase dbuf)
    __shared__ float sb1[128], sw2[128];
    const int t = threadIdx.x;
    const int lane = t & 63;
    const int wave = t >> 6;
    const int cc = lane & 31;     // edge column / A-row
    const int h  = lane >> 5;     // k-half
    if (t < 128) { sb1[t] = B1[t]; sw2[t] = W2[t]; }

    // ---- W1 strip -> f16 registers: wave w owns channels [w*32, w*32+32).
    f16x8 wf[16];
    {
        const float* wrow = W1 + (((wave << 5) + cc) << 8);   // 256 f32/row
#pragma unroll
        for (int kt = 0; kt < 8; ++kt) {
#pragma unroll
            for (int half = 0; half < 2; ++half) {
                const float* wp = wrow + (half << 7) + (kt << 4) + (h << 3);
                f32x4 a = *(const f32x4*)wp;
                f32x4 b = *(const f32x4*)(wp + 4);
                f16x8 f;
                f[0]=(_Float16)a[0]; f[1]=(_Float16)a[1]; f[2]=(_Float16)a[2]; f[3]=(_Float16)a[3];
                f[4]=(_Float16)b[0]; f[5]=(_Float16)b[1]; f[6]=(_Float16)b[2]; f[7]=(_Float16)b[3];
                wf[(kt << 1) + half] = f;
            }
        }
    }

    // staging geometry: instr i covers rows wave*16+i*4+(lane>>4);
    // slot chunk c = lane&15, global chunk = c ^ (r&15)
    const unsigned char* Pb = (const unsigned char*)P;
    const int* eb = ei + (wave < 2 ? 0 : N_EDGES - 32);   // dst waves offset
    const int rl = lane >> 4;
    const int rb0 = (wave << 4) + 0  + rl, rb1 = (wave << 4) + 4  + rl;
    const int rb2 = (wave << 4) + 8  + rl, rb3 = (wave << 4) + 12 + rl;
    const int xo0 = ((lane & 15) ^ (rb0 & 15)) << 4;
    const int xo1 = ((lane & 15) ^ (rb1 & 15)) << 4;
    const int xo2 = ((lane & 15) ^ (rb2 & 15)) << 4;
    const int xo3 = ((lane & 15) ^ (rb3 & 15)) << 4;
    const int lbo0 = (rb0 & ~3) << 8, lbo1 = (rb1 & ~3) << 8;
    const int lbo2 = (rb2 & ~3) << 8, lbo3 = (rb3 & ~3) << 8;
    const int cx = cc & 15;
    const float b2v = B2[0];
    const int t0 = blockIdx.x;

    int tl = t0, prev = -1, ph = 0;
    int nidx0, nidx1, nidx2, nidx3;

    // ---- prologue: stage T0->b0, T1->b1; load nidx for T2; one full drain.
    {
        const int* e0 = eb + (t0 << 5);
        int i0 = e0[rb0], i1 = e0[rb1], i2 = e0[rb2], i3 = e0[rb3];
        gload16(Pb + ((size_t)i0 << 8) + xo0, b0 + lbo0);
        gload16(Pb + ((size_t)i1 << 8) + xo1, b0 + lbo1);
        gload16(Pb + ((size_t)i2 << 8) + xo2, b0 + lbo2);
        gload16(Pb + ((size_t)i3 << 8) + xo3, b0 + lbo3);
    }
    {
        int tn = t0 + GRID; tn = tn < NT ? tn : NT - 1;
        const int* e1 = eb + (tn << 5);
        int i0 = e1[rb0], i1 = e1[rb1], i2 = e1[rb2], i3 = e1[rb3];
        gload16(Pb + ((size_t)i0 << 8) + xo0, b1 + lbo0);
        gload16(Pb + ((size_t)i1 << 8) + xo1, b1 + lbo1);
        gload16(Pb + ((size_t)i2 << 8) + xo2, b1 + lbo2);
        gload16(Pb + ((size_t)i3 << 8) + xo3, b1 + lbo3);
    }
    {
        int tn = t0 + 2 * GRID; tn = tn < NT ? tn : NT - 1;
        const int* e2 = eb + (tn << 5);
        nidx0 = e2[rb0]; nidx1 = e2[rb1]; nidx2 = e2[rb2]; nidx3 = e2[rb3];
    }
    __syncthreads();   // prologue drain: b0,b1 staged, tables ready

// One step: barrier (no vmcnt drain) -> store prev tile -> stage tl+2*GRID
// into BS (consumes nidx => compiler wait retires LAST step's loads — the
// counted-wait) -> load nidx for tl+3*GRID -> compute tl from BC with dual
// accumulators -> partials -> lgkmcnt(0).
#define STEP(BC, BS)                                                          \
    {                                                                         \
        asm volatile("s_waitcnt vmcnt(8)\n\ts_barrier" ::: "memory");         \
        if (prev >= 0 && t < 32) {                                            \
            const int pp = ph ^ 1;                                            \
            const float z = pr[pp][0][t] + pr[pp][1][t] + pr[pp][2][t]        \
                          + pr[pp][3][t] + b2v;                               \
            out[(prev << 5) + t] = 1.0f / (1.0f + __expf(-z));                \
        }                                                                     \
        gload16(Pb + ((size_t)nidx0 << 8) + xo0, (BS) + lbo0);                \
        gload16(Pb + ((size_t)nidx1 << 8) + xo1, (BS) + lbo1);                \
        gload16(Pb + ((size_t)nidx2 << 8) + xo2, (BS) + lbo2);                \
        gload16(Pb + ((size_t)nidx3 << 8) + xo3, (BS) + lbo3);                \
        {   int tn = tl + 3 * GRID; tn = tn < NT ? tn : NT - 1;               \
            const int* ebn = eb + (tn << 5);                                  \
            nidx0 = ebn[rb0]; nidx1 = ebn[rb1];                               \
            nidx2 = ebn[rb2]; nidx3 = ebn[rb3]; }                             \
        const unsigned char* xb = (BC) + (cc << 8);                           \
        const unsigned char* yb = (BC) + ((32 + cc) << 8);                    \
        f32x16 accp = {}, accd = {};                                          \
        _Pragma("unroll")                                                     \
        for (int kt = 0; kt < 8; ++kt) {                                      \
            const int co = (((kt << 1) + h) ^ cx) << 4;                       \
            const f16x8 xh = __builtin_bit_cast(f16x8, *(const u32x4*)(xb + co)); \
            const f16x8 yh = __builtin_bit_cast(f16x8, *(const u32x4*)(yb + co)); \
            const f16x8 bpv = xh * yh;                                        \
            const f16x8 bdv = xh - yh;                                        \
            accp = __builtin_amdgcn_mfma_f32_32x32x16_f16(wf[(kt << 1) + 0], bpv, accp, 0, 0, 0); \
            accd = __builtin_amdgcn_mfma_f32_32x32x16_f16(wf[(kt << 1) + 1], bdv, accd, 0, 0, 0); \
        }                                                                     \
        float partial = 0.f;                                                  \
        _Pragma("unroll")                                                     \
        for (int q = 0; q < 4; ++q) {                                         \
            const int chb = (wave << 5) + (q << 3) + (h << 2);                \
            const f32x4 bb = *(const f32x4*)(sb1 + chb);                      \
            const f32x4 ww = *(const f32x4*)(sw2 + chb);                      \
            _Pragma("unroll")                                                 \
            for (int rr = 0; rr < 4; ++rr) {                                  \
                const float hv = fmaxf(accp[(q << 2) + rr] + accd[(q << 2) + rr] + bb[rr], 0.f); \
                partial += hv * ww[rr];                                       \
            }                                                                 \
        }                                                                     \
        partial += __shfl_xor(partial, 32);                                   \
        if (h == 0) pr[ph][wave][cc] = partial;                               \
        asm volatile("s_waitcnt lgkmcnt(0)" ::: "memory");                    \
        prev = tl; tl += GRID; ph ^= 1;                                       \
    }

    while (tl < NT) {
        STEP(b0, b2);
        if (tl >= NT) break;
        STEP(b1, b0);
        if (tl >= NT) break;
        STEP(b2, b1);
    }
#undef STEP

    // ---- epilogue: store the last computed tile's output
    asm volatile("s_barrier" ::: "memory");
    if (prev >= 0 && t < 32) {
        const int pp = ph ^ 1;
        const float z = pr[pp][0][t] + pr[pp][1][t] + pr[pp][2][t]
                      + pr[pp][3][t] + b2v;
        out[(prev << 5) + t] = 1.0f / (1.0f + __expf(-z));
    }
}

extern "C" void kernel_launch(void* const* d_in, const int* in_sizes, int n_in,
                              void* d_out, int out_size, void* d_ws, size_t ws_size,
                              hipStream_t stream) {
    const float* nf   = (const float*)d_in[0];
    const int*   ei   = (const int*)d_in[1];
    const float* Wdim = (const float*)d_in[2];
    const float* bdim = (const float*)d_in[3];
    const float* W1   = (const float*)d_in[4];
    const float* b1   = (const float*)d_in[5];
    const float* W2   = (const float*)d_in[6];
    const float* b2   = (const float*)d_in[7];
    float* out = (float*)d_out;
    unsigned short* P = (unsigned short*)d_ws;        // 100000*128 f16 = 25.6 MB

    k_project<<<dim3(782), dim3(256), 0, stream>>>(nf, Wdim, bdim, P);
    k_edge<<<dim3(GRID), dim3(256), 0, stream>>>(P, ei, W1, b1, W2, b2, out);
}